// Round 10
// baseline (91.726 us; speedup 1.0000x reference)
//
#include <hip/hip_runtime.h>
#include <stdint.h>

// ============================================================================
// Bit-exact JAX Gibbs sampler — R9 resubmit (container died again).
// 4 chains/wave (occupancy 2x: 4096 waves, 4 blocks/CU) with verbatim R5-R8
// arithmetic. Slot packing: (q,t') -> lane 4*(t'&15)+q over 2 register sets;
// gumbels in 5 sets; one m32 output word per lane; 1-bpermute coalesced
// epilogue. pre_kernel unchanged from R8.
// ============================================================================
#define MIX_TIME 20
#define NCHAIN   16384   // S*B = 128*128
#define DDIM     512

// ws layout in 4-byte units
#define WS_TBL 0        // 80  (pad 128)
#define WS_SC  128      // 160
#define WS_T0  288      // 512
#define WS_U0  800      // 512
#define WS_ST0 1312     // 1 (pad 32)
#define WS_SZ0 1344     // 128
#define WS_C   1472     // 65536

struct U2 { uint32_t a, b; };

__device__ __forceinline__ uint32_t rotl32(uint32_t v, int r) {
  return (v << r) | (v >> (32 - r));
}

// Threefry-2x32, 20 rounds (JAX prng.py / Random123).
__device__ __forceinline__ U2 tf2x32(uint32_t k0, uint32_t k1, uint32_t x0, uint32_t x1) {
  const uint32_t ks2 = k0 ^ k1 ^ 0x1BD11BDAu;
  x0 += k0; x1 += k1;
  x0 += x1; x1 = rotl32(x1, 13); x1 ^= x0;
  x0 += x1; x1 = rotl32(x1, 15); x1 ^= x0;
  x0 += x1; x1 = rotl32(x1, 26); x1 ^= x0;
  x0 += x1; x1 = rotl32(x1,  6); x1 ^= x0;
  x0 += k1; x1 += ks2 + 1u;
  x0 += x1; x1 = rotl32(x1, 17); x1 ^= x0;
  x0 += x1; x1 = rotl32(x1, 29); x1 ^= x0;
  x0 += x1; x1 = rotl32(x1, 16); x1 ^= x0;
  x0 += x1; x1 = rotl32(x1, 24); x1 ^= x0;
  x0 += ks2; x1 += k0 + 2u;
  x0 += x1; x1 = rotl32(x1, 13); x1 ^= x0;
  x0 += x1; x1 = rotl32(x1, 15); x1 ^= x0;
  x0 += x1; x1 = rotl32(x1, 26); x1 ^= x0;
  x0 += x1; x1 = rotl32(x1,  6); x1 ^= x0;
  x0 += k0; x1 += k1 + 3u;
  x0 += x1; x1 = rotl32(x1, 17); x1 ^= x0;
  x0 += x1; x1 = rotl32(x1, 29); x1 ^= x0;
  x0 += x1; x1 = rotl32(x1, 16); x1 ^= x0;
  x0 += x1; x1 = rotl32(x1, 24); x1 ^= x0;
  x0 += k1; x1 += ks2 + 4u;
  x0 += x1; x1 = rotl32(x1, 13); x1 ^= x0;
  x0 += x1; x1 = rotl32(x1, 15); x1 ^= x0;
  x0 += x1; x1 = rotl32(x1, 26); x1 ^= x0;
  x0 += x1; x1 = rotl32(x1,  6); x1 ^= x0;
  x0 += ks2; x1 += k0 + 5u;
  return {x0, x1};
}

// partitionable threefry (validated bit-exact in R1-R8)
__device__ __forceinline__ uint32_t rbits32(uint32_t k0, uint32_t k1, uint32_t m) {
  U2 r = tf2x32(k0, k1, 0u, m);
  return r.a ^ r.b;
}
__device__ __forceinline__ U2 split_key(uint32_t k0, uint32_t k1, uint32_t idx) {
  return tf2x32(k0, k1, 0u, idx);
}

// gumbel from raw bits — expression identical to R1-R8 (bit-exact g)
__device__ __forceinline__ float gumbel_from(uint32_t bits) {
  float u = __uint_as_float(0x3f800000u | (bits >> 9)) - 1.0f;
  u = fmaxf(u + 1.17549435e-38f, 1.17549435e-38f);
  return -logf(-logf(u));
}

__device__ __forceinline__ float bpermf(int byteidx, float v) {
  return __int_as_float(__builtin_amdgcn_ds_bpermute(byteidx, __float_as_int(v)));
}
__device__ __forceinline__ uint32_t bpermu(int byteidx, uint32_t v) {
  return (uint32_t)__builtin_amdgcn_ds_bpermute(byteidx, (int)v);
}

// ============================================================================
// Kernel A (unchanged from R8): bid 0..19: one sort each (+sc row) |
// 20,21: T0 (+St0) | 22,23: U0 | 24..151: C z-batched slabs (+Sz0 in slab 0)
// ============================================================================
__global__ __launch_bounds__(256)
void pre_kernel(const float* __restrict__ A, const float* __restrict__ W,
                const float* __restrict__ z, uint32_t* __restrict__ wsu,
                float* __restrict__ wsf) {
  const int bid = blockIdx.x, tid = threadIdx.x;
  uint32_t* tbl = wsu + WS_TBL;
  uint32_t* sc  = wsu + WS_SC;
  float* T0  = wsf + WS_T0;
  float* U0  = wsf + WS_U0;
  float* St0 = wsf + WS_ST0;
  float* Sz0 = wsf + WS_SZ0;
  float* C   = wsf + WS_C;

  __shared__ float  sred[64];
  __shared__ float4 zs4[8][128];
  __shared__ float  credL[8][64];

  if (bid < MIX_TIME) {
    if (tid >= 64) return;
    const uint32_t t    = (uint32_t)bid;
    const uint32_t lane = (uint32_t)tid;
    const U2 K   = split_key(0u, 1u, t);
    const U2 ki  = split_key(K.a, K.b, 0u);
    const U2 ks  = split_key(K.a, K.b, 1u);
    const U2 sub = split_key(ki.a, ki.b, 1u);

    uint32_t k1 = 0xFFFFFFFFu, m1 = 0xFFFFFFFFu;
    uint32_t k2 = 0xFFFFFFFFu, m2 = 0xFFFFFFFFu;
    #pragma unroll
    for (int p = 0; p < 8; ++p) {
      const uint32_t m   = lane + 64u * (uint32_t)p;
      const uint32_t key = rbits32(sub.a, sub.b, m);
      const bool lt1 = (key < k1) || (key == k1 && m < m1);
      const bool lt2 = (key < k2) || (key == k2 && m < m2);
      if (lt1)      { k2 = k1; m2 = m1; k1 = key; m1 = m; }
      else if (lt2) { k2 = key; m2 = m; }
    }
    #pragma unroll
    for (int msk = 1; msk < 64; msk <<= 1) {
      const uint32_t ok1 = __shfl_xor((int)k1, msk, 64);
      const uint32_t om1 = __shfl_xor((int)m1, msk, 64);
      const uint32_t ok2 = __shfl_xor((int)k2, msk, 64);
      const uint32_t om2 = __shfl_xor((int)m2, msk, 64);
      const bool oless = (ok1 < k1) || (ok1 == k1 && om1 < m1);
      if (oless) {
        const bool l2 = (k1 < ok2) || (k1 == ok2 && m1 < om2);
        const uint32_t nk2 = l2 ? k1 : ok2, nm2 = l2 ? m1 : om2;
        k1 = ok1; m1 = om1; k2 = nk2; m2 = nm2;
      } else {
        const bool l2 = (ok1 < k2) || (ok1 == k2 && om1 < m2);
        if (l2) { k2 = ok1; m2 = om1; }
      }
    }
    if (lane == 0) {
      tbl[4u * t + 0u] = m1;
      tbl[4u * t + 1u] = m2;
      tbl[4u * t + 2u] = ks.a;
      tbl[4u * t + 3u] = ks.b;
      sc[8u * t + 0u] = m1;
      sc[8u * t + 1u] = m2;
      sc[8u * t + 6u] = 0u;
      sc[8u * t + 7u] = 0u;
    }
    if (lane < 4) {   // Aii, Aij, Aji, Ajj
      const uint32_t r = (lane < 2) ? m1 : m2;
      const uint32_t c = (lane & 1) ? m2 : m1;
      sc[8u * t + 2u + lane] = __float_as_uint(A[(size_t)r * DDIM + c]);
    }
    return;
  }

  if (bid <= MIX_TIME + 1) {         // T0[e] = sum_{d<64} A[d,e] (+St0)
    const int e = (bid - MIX_TIME) * 256 + tid;
    float s = 0.f;
    #pragma unroll 1
    for (int d = 0; d < 64; ++d) s += A[(size_t)d * DDIM + e];
    T0[e] = s;
    if (bid == MIX_TIME) {
      if (tid < 64) sred[tid] = s;
      __syncthreads();
      if (tid == 0) {
        float q = 0.f;
        #pragma unroll 1
        for (int e2 = 0; e2 < 64; ++e2) q += sred[e2];
        St0[0] = q;
      }
    }
    return;
  }

  if (bid <= MIX_TIME + 3) {         // U0[d] = sum_{e<64} A[d,e]
    const int d = (bid - MIX_TIME - 2) * 256 + tid;
    const float4* Ar = reinterpret_cast<const float4*>(A + (size_t)d * DDIM);
    float s = 0.f;
    #pragma unroll
    for (int k = 0; k < 16; ++k) {
      const float4 v = Ar[k];
      s += v.x; s += v.y; s += v.z; s += v.w;
    }
    U0[d] = s;
    return;
  }

  // ---- C[b][d] = sum_k W[d,k] z[b,k]: block = (bg of 8 b's, slab of 64 d's) ----
  const int cb = bid - (MIX_TIME + 4);  // 0..127
  const int bg = cb >> 3, slab = cb & 7;
  #pragma unroll
  for (int k = 0; k < 4; ++k) {
    const int idx = tid + 256 * k;      // 0..1023 = brow*128 + col4
    const int br = idx >> 7, c4i = idx & 127;
    zs4[br][c4i] = reinterpret_cast<const float4*>(z + (size_t)(bg * 8 + br) * DDIM)[c4i];
  }
  __syncthreads();
  const int r = tid & 63;
  const int h = tid >> 6;               // b pair {2h, 2h+1}
  const int d = slab * 64 + r;
  const float4* Wr = reinterpret_cast<const float4*>(W + (size_t)d * DDIM);
  float s0 = 0.f, s1 = 0.f;
  #pragma unroll 4
  for (int k = 0; k < 128; ++k) {
    const float4 w = Wr[k];
    const float4 za = zs4[2 * h][k], zb = zs4[2 * h + 1][k];
    s0 = fmaf(w.x, za.x, s0); s0 = fmaf(w.y, za.y, s0);
    s0 = fmaf(w.z, za.z, s0); s0 = fmaf(w.w, za.w, s0);
    s1 = fmaf(w.x, zb.x, s1); s1 = fmaf(w.y, zb.y, s1);
    s1 = fmaf(w.z, zb.z, s1); s1 = fmaf(w.w, zb.w, s1);
  }
  C[(size_t)(bg * 8 + 2 * h) * DDIM + d]     = s0;
  C[(size_t)(bg * 8 + 2 * h + 1) * DDIM + d] = s1;
  if (slab == 0) { credL[2 * h][r] = s0; credL[2 * h + 1][r] = s1; }
  __syncthreads();
  if (slab == 0 && tid < 8) {
    float s = 0.f;
    #pragma unroll 1
    for (int e = 0; e < 64; ++e) s += credL[tid][e];
    Sz0[bg * 8 + tid] = s;
  }
}

// ============================================================================
// Kernel B: sampler, 4 chains per wave (1024 blocks -> 4 waves/SIMD).
//   algebra chain ql = l>>4 (16-lane groups; combos in aligned 4-lane subgrps)
//   state slot (q, t'): lane = 4*(t'&15) + q, reg set = t'>>4 (2 sets)
//   gumbels: 5 sets; set k lane l = (t=4k+(l>>4), q=(l>>2)&3, c=l&3)
//   output: lane 16q + r owns bits [32r, 32r+32) of chain q (single m32)
// ============================================================================
__global__ __launch_bounds__(256)
void gibbs4_kernel(const float* __restrict__ A,
                   const uint32_t* __restrict__ wsu,
                   const float* __restrict__ wsf,
                   float* __restrict__ out) {
  const int tid = threadIdx.x;
  const int l = tid & 63, wv = tid >> 6;
  const uint32_t* tbl = wsu + WS_TBL;
  const uint32_t* sc  = wsu + WS_SC;
  const float* T0w  = wsf + WS_T0;
  const float* U0w  = wsf + WS_U0;
  const float* St0w = wsf + WS_ST0;
  const float* Sz0w = wsf + WS_SZ0;
  const float* Cw   = wsf + WS_C;

  __shared__ __align__(16) float gg[3200];   // [0,1600)=G, [1600,3200)=Gt
  __shared__ uint32_t tblL[80];
  if (tid < 80) tblL[tid] = tbl[tid];
  __syncthreads();
  #pragma unroll 1
  for (int p = tid; p < 1600; p += 256) {
    const int r = p / 40, c = p % 40;
    const uint32_t cr = tblL[4 * (r >> 1) + (r & 1)];
    const uint32_t cc = tblL[4 * (c >> 1) + (c & 1)];
    gg[p]        = A[(size_t)cr * DDIM + cc];
    gg[1600 + p] = A[(size_t)cc * DDIM + cr];
  }

  const int ql = l >> 4;                 // algebra chain
  const int qs = l & 3;                  // slot chain
  const int c4 = l & 3;                  // combo
  const int r16 = l & 15;                // output word index within chain
  const uint32_t chainbase = ((uint32_t)blockIdx.x * 4u + (uint32_t)wv) * 4u;
  const uint32_t chain_l = chainbase + (uint32_t)ql;
  const uint32_t b_l = chain_l & 127u;
  const uint32_t b_s = (chainbase + (uint32_t)qs) & 127u;
  const float fa  = (float)((c4 >> 1) & 1);
  const float fb  = (float)(c4 & 1);
  const float fab = fa * fb;

  // ---- state sets: slot (q=qs, t' = 16k + (l>>2)); dead slots clamped ----
  float fTi[2], fTj[2], fUi[2], fUj[2], fci[2], fcj[2], fxi[2], fxj[2];
  uint32_t iiK[2], jjK[2];
  const float* ggb[2];
  #pragma unroll
  for (int k = 0; k < 2; ++k) {
    const int tp = 16 * k + (l >> 2);
    const int tc = (tp < MIX_TIME) ? tp : 0;
    const uint32_t i = sc[8 * tc], j = sc[8 * tc + 1];
    iiK[k] = i; jjK[k] = j;
    fTi[k] = T0w[i];  fTj[k] = T0w[j];
    fUi[k] = U0w[i];  fUj[k] = U0w[j];
    fci[k] = Cw[(size_t)b_s * DDIM + i];
    fcj[k] = Cw[(size_t)b_s * DDIM + j];
    fxi[k] = (i < 64u) ? 1.f : 0.f;
    fxj[k] = (j < 64u) ? 1.f : 0.f;
    ggb[k] = &gg[2 * tc];
  }
  float St = St0w[0];
  float Sz = Sz0w[b_l];
  uint32_t m32 = (r16 < 2) ? 0xFFFFFFFFu : 0u;   // x0: elements [0,64) set

  // ---- batched gumbels: 5 regs x 64 lanes = 320 = 4 chains x 80 ----
  float garr[5];
  #pragma unroll
  for (int k = 0; k < 5; ++k) {
    const int f = 64 * k + l;
    const int t = f >> 4;
    const uint32_t qg = ((uint32_t)l >> 2) & 3u;
    const uint32_t m  = (chainbase + qg) * 4u + (uint32_t)(l & 3);
    garr[k] = gumbel_from(rbits32(tbl[4 * t + 2], tbl[4 * t + 3], m));
  }
  __syncthreads();

  #pragma unroll
  for (int t = 0; t < MIX_TIME; ++t) {
    const int kS   = t >> 4;
    const int bidx = (4 * (t & 15) + ql) << 2;
    const float Ti  = bpermf(bidx, fTi[kS]);
    const float Tj  = bpermf(bidx, fTj[kS]);
    const float Ui  = bpermf(bidx, fUi[kS]);
    const float Uj  = bpermf(bidx, fUj[kS]);
    const float cib = bpermf(bidx, fci[kS]);
    const float cjb = bpermf(bidx, fcj[kS]);
    const float xi  = bpermf(bidx, fxi[kS]);
    const float xj  = bpermf(bidx, fxj[kS]);
    const float gv  = bpermf((16 * (t & 3) + 4 * ql + c4) << 2, garr[t >> 2]);

    const uint32_t ii = sc[8 * t], jj = sc[8 * t + 1];
    const float Aii = __uint_as_float(sc[8 * t + 2]);
    const float Aij = __uint_as_float(sc[8 * t + 3]);
    const float Aji = __uint_as_float(sc[8 * t + 4]);
    const float Ajj = __uint_as_float(sc[8 * t + 5]);

    // ---- algebra (R4-R8 verbatim) ----
    const float si   = Ui - xi * Aii - xj * Aij;
    const float sj   = Uj - xi * Aji - xj * Ajj;
    const float sTR  = St - xi * Ti - xj * Tj;
    const float szR  = Sz - xi * cib - xj * cjb;
    const float QR   = sTR - xi * si - xj * sj;
    const float coli = Ti - xi * Aii - xj * Aji;
    const float colj = Tj - xi * Aij - xj * Ajj;
    const float base = QR + szR;
    const float gi   = si + coli + Aii + cib;
    const float gj   = sj + colj + Ajj + cjb;
    const float gij  = Aij + Aji;
    const float v    = gv + (base + fa * gi + fb * gj + fab * gij);

    // ---- first-max argmax over 4 combos (aligned 4-lane butterflies) ----
    float bv = v; int bestc = c4;
    #pragma unroll
    for (int msk = 1; msk < 4; msk <<= 1) {
      const float ov = __shfl_xor(bv, msk, 64);
      const int   oc = __shfl_xor(bestc, msk, 64);
      if (ov > bv || (ov == bv && oc < bestc)) { bv = ov; bestc = oc; }
    }

    const int ian = (bestc >> 1) & 1, ibn = bestc & 1;
    const float fan = (float)ian, fbn = (float)ibn;
    const float fdi = fan - xi, fdj = fbn - xj;

    St = St + fdi * Ti + fdj * Tj
            + fdi * (si + fan * Aii + fbn * Aij)
            + fdj * (sj + fan * Aji + fbn * Ajj);
    Sz = Sz + fdi * cib + fdj * cjb;

    // ---- carry (fdi,fdj,bestc) of chain qs to slot-owner lanes ----
    const int pk  = ((int)fdi + 1) | (((int)fdj + 1) << 2) | (bestc << 4);
    const int pks = __builtin_amdgcn_ds_bpermute(qs << 6, pk);
    const float fdi_s = (float)((pks & 3) - 1);
    const float fdj_s = (float)(((pks >> 2) & 3) - 1);
    const float fan_s = (float)((pks >> 5) & 1);
    const float fbn_s = (float)((pks >> 4) & 1);

    // ---- slot updates; set k live while t < 16k+15 (dead sets never read) --
    #pragma unroll
    for (int k = 0; k < 2; ++k) {
      if (t < 16 * k + 15) {
        const float2 ga = *reinterpret_cast<const float2*>(ggb[k] + 80 * t);
        const float2 gB = *reinterpret_cast<const float2*>(ggb[k] + 80 * t + 40);
        const float2 gc = *reinterpret_cast<const float2*>(ggb[k] + 1600 + 80 * t);
        const float2 gd = *reinterpret_cast<const float2*>(ggb[k] + 1600 + 80 * t + 40);
        fTi[k] = fmaf(fdi_s, ga.x, fmaf(fdj_s, gB.x, fTi[k]));
        fTj[k] = fmaf(fdi_s, ga.y, fmaf(fdj_s, gB.y, fTj[k]));
        fUi[k] = fmaf(fdi_s, gc.x, fmaf(fdj_s, gd.x, fUi[k]));
        fUj[k] = fmaf(fdi_s, gc.y, fmaf(fdj_s, gd.y, fUj[k]));
        fxi[k] = (iiK[k] == ii) ? fan_s : fxi[k];
        fxi[k] = (iiK[k] == jj) ? fbn_s : fxi[k];
        fxj[k] = (jjK[k] == ii) ? fan_s : fxj[k];
        fxj[k] = (jjK[k] == jj) ? fbn_s : fxj[k];
      }
    }

    // ---- output-bit maintenance: lane 16q+r owns bits [32r,32r+32) ----
    {
      const uint32_t ib = 1u << (ii & 31u);
      if ((uint32_t)r16 == (ii >> 5))
        m32 = (m32 & ~ib) | ((uint32_t)(-(int)ian) & ib);
      const uint32_t jb = 1u << (jj & 31u);
      if ((uint32_t)r16 == (jj >> 5))
        m32 = (m32 & ~jb) | ((uint32_t)(-(int)ibn) & jb);
    }
  }

  // ---- output: fully-coalesced stores (bit-identical values, repacked) ----
  // Store g: lane l writes float4 index f = 64g + l of the wave's 4-chain
  // region (1 KB contiguous per instruction). Owner lane = 16*(f>>7) +
  // ((f&127)>>3); nibble shift = 4*((f&127)&7).
  {
    float4* wavebase = reinterpret_cast<float4*>(out + (size_t)chainbase * DDIM);
    #pragma unroll
    for (int g = 0; g < 8; ++g) {
      const int f  = 64 * g + l;
      const int e4 = f & 127;
      const int owner = 16 * (f >> 7) + (e4 >> 3);
      const uint32_t w = bpermu(owner << 2, m32);
      const uint32_t nib = (w >> (4 * (e4 & 7))) & 0xFu;
      float4 o;
      o.x = (float)( nib       & 1u);
      o.y = (float)((nib >> 1) & 1u);
      o.z = (float)((nib >> 2) & 1u);
      o.w = (float)((nib >> 3) & 1u);
      wavebase[f] = o;
    }
  }
}

extern "C" void kernel_launch(void* const* d_in, const int* in_sizes, int n_in,
                              void* d_out, int out_size, void* d_ws, size_t ws_size,
                              hipStream_t stream) {
  const float* z = (const float*)d_in[0];   // (128, 512)
  const float* A = (const float*)d_in[1];   // (512, 512)
  const float* W = (const float*)d_in[2];   // (512, 512)
  float* out = (float*)d_out;               // (128, 128, 512)
  uint32_t* wsu = (uint32_t*)d_ws;
  float*    wsf = (float*)d_ws;

  hipLaunchKernelGGL(pre_kernel, dim3(MIX_TIME + 4 + 128), dim3(256), 0, stream,
                     A, W, z, wsu, wsf);
  hipLaunchKernelGGL(gibbs4_kernel, dim3(NCHAIN / 16), dim3(256), 0, stream,
                     A, wsu, wsf, out);
}

// Round 11
// 49.203 us; speedup vs baseline: 1.8642x; 1.8642x over previous
//
#include <hip/hip_runtime.h>
#include <stdint.h>

// ============================================================================
// Bit-exact JAX Gibbs sampler — R11: R8 8-chain layout with ZERO post-algebra
// cross-lane ops. Slot chain == algebra chain (slot (q,t') -> lane 8q+(t'&7)),
// so decisions are local to slot owners (carry bpermute deleted); argmax is a
// local scan over all 4 combo values (gumbels fetched in the same bpermute
// batch). All produced values bit-identical to R7/R8 (absmax 0.0).
// ============================================================================
#define MIX_TIME 20
#define NCHAIN   16384   // S*B = 128*128
#define DDIM     512

// ws layout in 4-byte units
#define WS_TBL 0        // 80  (pad 128)
#define WS_SC  128      // 160
#define WS_T0  288      // 512
#define WS_U0  800      // 512
#define WS_ST0 1312     // 1 (pad 32)
#define WS_SZ0 1344     // 128
#define WS_C   1472     // 65536

struct U2 { uint32_t a, b; };

__device__ __forceinline__ uint32_t rotl32(uint32_t v, int r) {
  return (v << r) | (v >> (32 - r));
}

// Threefry-2x32, 20 rounds (JAX prng.py / Random123).
__device__ __forceinline__ U2 tf2x32(uint32_t k0, uint32_t k1, uint32_t x0, uint32_t x1) {
  const uint32_t ks2 = k0 ^ k1 ^ 0x1BD11BDAu;
  x0 += k0; x1 += k1;
  x0 += x1; x1 = rotl32(x1, 13); x1 ^= x0;
  x0 += x1; x1 = rotl32(x1, 15); x1 ^= x0;
  x0 += x1; x1 = rotl32(x1, 26); x1 ^= x0;
  x0 += x1; x1 = rotl32(x1,  6); x1 ^= x0;
  x0 += k1; x1 += ks2 + 1u;
  x0 += x1; x1 = rotl32(x1, 17); x1 ^= x0;
  x0 += x1; x1 = rotl32(x1, 29); x1 ^= x0;
  x0 += x1; x1 = rotl32(x1, 16); x1 ^= x0;
  x0 += x1; x1 = rotl32(x1, 24); x1 ^= x0;
  x0 += ks2; x1 += k0 + 2u;
  x0 += x1; x1 = rotl32(x1, 13); x1 ^= x0;
  x0 += x1; x1 = rotl32(x1, 15); x1 ^= x0;
  x0 += x1; x1 = rotl32(x1, 26); x1 ^= x0;
  x0 += x1; x1 = rotl32(x1,  6); x1 ^= x0;
  x0 += k0; x1 += k1 + 3u;
  x0 += x1; x1 = rotl32(x1, 17); x1 ^= x0;
  x0 += x1; x1 = rotl32(x1, 29); x1 ^= x0;
  x0 += x1; x1 = rotl32(x1, 16); x1 ^= x0;
  x0 += x1; x1 = rotl32(x1, 24); x1 ^= x0;
  x0 += k1; x1 += ks2 + 4u;
  x0 += x1; x1 = rotl32(x1, 13); x1 ^= x0;
  x0 += x1; x1 = rotl32(x1, 15); x1 ^= x0;
  x0 += x1; x1 = rotl32(x1, 26); x1 ^= x0;
  x0 += x1; x1 = rotl32(x1,  6); x1 ^= x0;
  x0 += ks2; x1 += k0 + 5u;
  return {x0, x1};
}

// partitionable threefry (validated bit-exact in R1-R10)
__device__ __forceinline__ uint32_t rbits32(uint32_t k0, uint32_t k1, uint32_t m) {
  U2 r = tf2x32(k0, k1, 0u, m);
  return r.a ^ r.b;
}
__device__ __forceinline__ U2 split_key(uint32_t k0, uint32_t k1, uint32_t idx) {
  return tf2x32(k0, k1, 0u, idx);
}

// gumbel from raw bits — expression identical to R1-R10 (bit-exact g)
__device__ __forceinline__ float gumbel_from(uint32_t bits) {
  float u = __uint_as_float(0x3f800000u | (bits >> 9)) - 1.0f;
  u = fmaxf(u + 1.17549435e-38f, 1.17549435e-38f);
  return -logf(-logf(u));
}

__device__ __forceinline__ float bpermf(int byteidx, float v) {
  return __int_as_float(__builtin_amdgcn_ds_bpermute(byteidx, __float_as_int(v)));
}
__device__ __forceinline__ uint32_t bpermu(int byteidx, uint32_t v) {
  return (uint32_t)__builtin_amdgcn_ds_bpermute(byteidx, (int)v);
}

// ============================================================================
// Kernel A (unchanged from R8): bid 0..19: one sort each (+sc row) |
// 20,21: T0 (+St0) | 22,23: U0 | 24..151: C z-batched slabs (+Sz0 in slab 0)
// ============================================================================
__global__ __launch_bounds__(256)
void pre_kernel(const float* __restrict__ A, const float* __restrict__ W,
                const float* __restrict__ z, uint32_t* __restrict__ wsu,
                float* __restrict__ wsf) {
  const int bid = blockIdx.x, tid = threadIdx.x;
  uint32_t* tbl = wsu + WS_TBL;
  uint32_t* sc  = wsu + WS_SC;
  float* T0  = wsf + WS_T0;
  float* U0  = wsf + WS_U0;
  float* St0 = wsf + WS_ST0;
  float* Sz0 = wsf + WS_SZ0;
  float* C   = wsf + WS_C;

  __shared__ float  sred[64];
  __shared__ float4 zs4[8][128];
  __shared__ float  credL[8][64];

  if (bid < MIX_TIME) {
    if (tid >= 64) return;
    const uint32_t t    = (uint32_t)bid;
    const uint32_t lane = (uint32_t)tid;
    const U2 K   = split_key(0u, 1u, t);
    const U2 ki  = split_key(K.a, K.b, 0u);
    const U2 ks  = split_key(K.a, K.b, 1u);
    const U2 sub = split_key(ki.a, ki.b, 1u);

    uint32_t k1 = 0xFFFFFFFFu, m1 = 0xFFFFFFFFu;
    uint32_t k2 = 0xFFFFFFFFu, m2 = 0xFFFFFFFFu;
    #pragma unroll
    for (int p = 0; p < 8; ++p) {
      const uint32_t m   = lane + 64u * (uint32_t)p;
      const uint32_t key = rbits32(sub.a, sub.b, m);
      const bool lt1 = (key < k1) || (key == k1 && m < m1);
      const bool lt2 = (key < k2) || (key == k2 && m < m2);
      if (lt1)      { k2 = k1; m2 = m1; k1 = key; m1 = m; }
      else if (lt2) { k2 = key; m2 = m; }
    }
    #pragma unroll
    for (int msk = 1; msk < 64; msk <<= 1) {
      const uint32_t ok1 = __shfl_xor((int)k1, msk, 64);
      const uint32_t om1 = __shfl_xor((int)m1, msk, 64);
      const uint32_t ok2 = __shfl_xor((int)k2, msk, 64);
      const uint32_t om2 = __shfl_xor((int)m2, msk, 64);
      const bool oless = (ok1 < k1) || (ok1 == k1 && om1 < m1);
      if (oless) {
        const bool l2 = (k1 < ok2) || (k1 == ok2 && m1 < om2);
        const uint32_t nk2 = l2 ? k1 : ok2, nm2 = l2 ? m1 : om2;
        k1 = ok1; m1 = om1; k2 = nk2; m2 = nm2;
      } else {
        const bool l2 = (ok1 < k2) || (ok1 == k2 && om1 < m2);
        if (l2) { k2 = ok1; m2 = om1; }
      }
    }
    if (lane == 0) {
      tbl[4u * t + 0u] = m1;
      tbl[4u * t + 1u] = m2;
      tbl[4u * t + 2u] = ks.a;
      tbl[4u * t + 3u] = ks.b;
      sc[8u * t + 0u] = m1;
      sc[8u * t + 1u] = m2;
      sc[8u * t + 6u] = 0u;
      sc[8u * t + 7u] = 0u;
    }
    if (lane < 4) {   // Aii, Aij, Aji, Ajj
      const uint32_t r = (lane < 2) ? m1 : m2;
      const uint32_t c = (lane & 1) ? m2 : m1;
      sc[8u * t + 2u + lane] = __float_as_uint(A[(size_t)r * DDIM + c]);
    }
    return;
  }

  if (bid <= MIX_TIME + 1) {         // T0[e] = sum_{d<64} A[d,e] (+St0)
    const int e = (bid - MIX_TIME) * 256 + tid;
    float s = 0.f;
    #pragma unroll 1
    for (int d = 0; d < 64; ++d) s += A[(size_t)d * DDIM + e];
    T0[e] = s;
    if (bid == MIX_TIME) {
      if (tid < 64) sred[tid] = s;
      __syncthreads();
      if (tid == 0) {
        float q = 0.f;
        #pragma unroll 1
        for (int e2 = 0; e2 < 64; ++e2) q += sred[e2];
        St0[0] = q;
      }
    }
    return;
  }

  if (bid <= MIX_TIME + 3) {         // U0[d] = sum_{e<64} A[d,e]
    const int d = (bid - MIX_TIME - 2) * 256 + tid;
    const float4* Ar = reinterpret_cast<const float4*>(A + (size_t)d * DDIM);
    float s = 0.f;
    #pragma unroll
    for (int k = 0; k < 16; ++k) {
      const float4 v = Ar[k];
      s += v.x; s += v.y; s += v.z; s += v.w;
    }
    U0[d] = s;
    return;
  }

  // ---- C[b][d] = sum_k W[d,k] z[b,k]: block = (bg of 8 b's, slab of 64 d's) ----
  const int cb = bid - (MIX_TIME + 4);  // 0..127
  const int bg = cb >> 3, slab = cb & 7;
  #pragma unroll
  for (int k = 0; k < 4; ++k) {
    const int idx = tid + 256 * k;      // 0..1023 = brow*128 + col4
    const int br = idx >> 7, c4i = idx & 127;
    zs4[br][c4i] = reinterpret_cast<const float4*>(z + (size_t)(bg * 8 + br) * DDIM)[c4i];
  }
  __syncthreads();
  const int r = tid & 63;
  const int h = tid >> 6;               // b pair {2h, 2h+1}
  const int d = slab * 64 + r;
  const float4* Wr = reinterpret_cast<const float4*>(W + (size_t)d * DDIM);
  float s0 = 0.f, s1 = 0.f;
  #pragma unroll 4
  for (int k = 0; k < 128; ++k) {
    const float4 w = Wr[k];
    const float4 za = zs4[2 * h][k], zb = zs4[2 * h + 1][k];
    s0 = fmaf(w.x, za.x, s0); s0 = fmaf(w.y, za.y, s0);
    s0 = fmaf(w.z, za.z, s0); s0 = fmaf(w.w, za.w, s0);
    s1 = fmaf(w.x, zb.x, s1); s1 = fmaf(w.y, zb.y, s1);
    s1 = fmaf(w.z, zb.z, s1); s1 = fmaf(w.w, zb.w, s1);
  }
  C[(size_t)(bg * 8 + 2 * h) * DDIM + d]     = s0;
  C[(size_t)(bg * 8 + 2 * h + 1) * DDIM + d] = s1;
  if (slab == 0) { credL[2 * h][r] = s0; credL[2 * h + 1][r] = s1; }
  __syncthreads();
  if (slab == 0 && tid < 8) {
    float s = 0.f;
    #pragma unroll 1
    for (int e = 0; e < 64; ++e) s += credL[tid][e];
    Sz0[bg * 8 + tid] = s;
  }
}

// ============================================================================
// Kernel B: sampler, 8 chains/wave. Chain q = lanes 8q..8q+7 (algebra, slots,
// output bits all on the same lanes -> decisions local). Slot (q,t') at lane
// 8q + (t'&7), reg set t'>>3. Per step: one batched LDS wait (12 bpermutes +
// slot-update ds_reads), then pure VALU.
// ============================================================================
__global__ __launch_bounds__(256)
void gibbs8_kernel(const float* __restrict__ A,
                   const uint32_t* __restrict__ wsu,
                   const float* __restrict__ wsf,
                   float* __restrict__ out) {
  const int tid = threadIdx.x;
  const int l = tid & 63, wv = tid >> 6;
  const uint32_t* tbl = wsu + WS_TBL;
  const uint32_t* sc  = wsu + WS_SC;
  const float* T0w  = wsf + WS_T0;
  const float* U0w  = wsf + WS_U0;
  const float* St0w = wsf + WS_ST0;
  const float* Sz0w = wsf + WS_SZ0;
  const float* Cw   = wsf + WS_C;

  __shared__ __align__(16) float gg[3200];   // [0,1600)=G, [1600,3200)=Gt
  __shared__ uint32_t tblL[80];
  if (tid < 80) tblL[tid] = tbl[tid];
  __syncthreads();
  #pragma unroll 1
  for (int p = tid; p < 1600; p += 256) {
    const int r = p / 40, c = p % 40;
    const uint32_t cr = tblL[4 * (r >> 1) + (r & 1)];
    const uint32_t cc = tblL[4 * (c >> 1) + (c & 1)];
    gg[p]        = A[(size_t)cr * DDIM + cc];
    gg[1600 + p] = A[(size_t)cc * DDIM + cr];
  }

  const int ql  = l >> 3;   // chain (algebra + slots + output bits)
  const int seg = l & 7;    // slot t'-low-bits / output segment
  const uint32_t chainbase = ((uint32_t)blockIdx.x * 4u + (uint32_t)wv) * 8u;
  const uint32_t chain_l = chainbase + (uint32_t)ql;
  const uint32_t b_l = chain_l & 127u;

  // ---- state: slot (q=ql, t' = 8k + seg); values identical to R8's slots ----
  float fTi[3], fTj[3], fUi[3], fUj[3], fci[3], fcj[3], fxi[3], fxj[3];
  uint32_t iiK[3], jjK[3];
  const float* ggb[3];
  #pragma unroll
  for (int k = 0; k < 3; ++k) {
    const int tp = 8 * k + seg;
    const int tc = (tp < MIX_TIME) ? tp : 0;
    const uint32_t i = sc[8 * tc], j = sc[8 * tc + 1];
    iiK[k] = i; jjK[k] = j;
    fTi[k] = T0w[i];  fTj[k] = T0w[j];
    fUi[k] = U0w[i];  fUj[k] = U0w[j];
    fci[k] = Cw[(size_t)b_l * DDIM + i];
    fcj[k] = Cw[(size_t)b_l * DDIM + j];
    fxi[k] = (i < 64u) ? 1.f : 0.f;
    fxj[k] = (j < 64u) ? 1.f : 0.f;
    ggb[k] = &gg[2 * tc];
  }
  float St = St0w[0];
  float Sz = Sz0w[b_l];
  uint32_t mlo = (seg == 0) ? 0xFFFFFFFFu : 0u;
  uint32_t mhi = mlo;

  // ---- batched gumbels (layout unchanged from R8):
  //      reg k, lane l holds (t = 2k+(l>>5), q = (l&31)>>2, c = l&3) ----
  float garr[10];
  #pragma unroll
  for (int k = 0; k < 10; ++k) {
    const int f = 64 * k + l;
    const int t = f >> 5;
    const uint32_t qg = ((uint32_t)l & 31u) >> 2;
    const uint32_t m  = (chainbase + qg) * 4u + (uint32_t)(l & 3);
    garr[k] = gumbel_from(rbits32(tbl[4 * t + 2], tbl[4 * t + 3], m));
  }
  __syncthreads();

  #pragma unroll
  for (int t = 0; t < MIX_TIME; ++t) {
    const int kS = t >> 3;
    // within-group broadcast from slot-owner lane 8*ql + (t&7)
    const int bidx = ((l & 0x38) + (t & 7)) << 2;
    const float Ti  = bpermf(bidx, fTi[kS]);
    const float Tj  = bpermf(bidx, fTj[kS]);
    const float Ui  = bpermf(bidx, fUi[kS]);
    const float Uj  = bpermf(bidx, fUj[kS]);
    const float cib = bpermf(bidx, fci[kS]);
    const float cjb = bpermf(bidx, fcj[kS]);
    const float xi  = bpermf(bidx, fxi[kS]);
    const float xj  = bpermf(bidx, fxj[kS]);
    // all 4 combo gumbels of chain ql (source lanes 32*(t&1) + 4*ql + c)
    const int gq = ((t & 1) << 7) + (ql << 4);
    const float gv0 = bpermf(gq + 0,  garr[t >> 1]);
    const float gv1 = bpermf(gq + 4,  garr[t >> 1]);
    const float gv2 = bpermf(gq + 8,  garr[t >> 1]);
    const float gv3 = bpermf(gq + 12, garr[t >> 1]);

    const uint32_t ii = sc[8 * t], jj = sc[8 * t + 1];
    const float Aii = __uint_as_float(sc[8 * t + 2]);
    const float Aij = __uint_as_float(sc[8 * t + 3]);
    const float Aji = __uint_as_float(sc[8 * t + 4]);
    const float Ajj = __uint_as_float(sc[8 * t + 5]);

    // ---- algebra (R4-R8 verbatim) ----
    const float si   = Ui - xi * Aii - xj * Aij;
    const float sj   = Uj - xi * Aji - xj * Ajj;
    const float sTR  = St - xi * Ti - xj * Tj;
    const float szR  = Sz - xi * cib - xj * cjb;
    const float QR   = sTR - xi * si - xj * sj;
    const float coli = Ti - xi * Aii - xj * Aji;
    const float colj = Tj - xi * Aij - xj * Ajj;
    const float base = QR + szR;
    const float gi   = si + coli + Aii + cib;
    const float gj   = sj + colj + Ajj + cjb;
    const float gij  = Aij + Aji;

    // ---- all 4 combo values locally (fma(0/1,x,y) == add identities:
    //      bit-equal to R8's per-lane values; ±0 cannot flip comparisons) ----
    const float v0 = gv0 + base;
    const float v1 = gv1 + (base + gj);
    const float v2 = gv2 + (base + gi);
    const float v3 = gv3 + (base + gi + gj + gij);

    // ---- first-max argmax, purely local (strict > keeps lowest index) ----
    int bestc = 0; float bv = v0;
    if (v1 > bv) { bv = v1; bestc = 1; }
    if (v2 > bv) { bv = v2; bestc = 2; }
    if (v3 > bv) { bv = v3; bestc = 3; }

    const int ian = (bestc >> 1) & 1, ibn = bestc & 1;
    const float fan = (float)ian, fbn = (float)ibn;
    const float fdi = fan - xi, fdj = fbn - xj;

    St = St + fdi * Ti + fdj * Tj
            + fdi * (si + fan * Aii + fbn * Aij)
            + fdj * (sj + fan * Aji + fbn * Ajj);
    Sz = Sz + fdi * cib + fdj * cjb;

    // ---- slot updates: decision is LOCAL (slot chain == ql).
    //      set k live while t < 8k+7 (dead sets never broadcast again) ----
    #pragma unroll
    for (int k = 0; k < 3; ++k) {
      if (t < 8 * k + 7) {
        const float2 ga = *reinterpret_cast<const float2*>(ggb[k] + 80 * t);
        const float2 gB = *reinterpret_cast<const float2*>(ggb[k] + 80 * t + 40);
        const float2 gc = *reinterpret_cast<const float2*>(ggb[k] + 1600 + 80 * t);
        const float2 gd = *reinterpret_cast<const float2*>(ggb[k] + 1600 + 80 * t + 40);
        fTi[k] = fmaf(fdi, ga.x, fmaf(fdj, gB.x, fTi[k]));
        fTj[k] = fmaf(fdi, ga.y, fmaf(fdj, gB.y, fTj[k]));
        fUi[k] = fmaf(fdi, gc.x, fmaf(fdj, gd.x, fUi[k]));
        fUj[k] = fmaf(fdi, gc.y, fmaf(fdj, gd.y, fUj[k]));
        fxi[k] = (iiK[k] == ii) ? fan : fxi[k];
        fxi[k] = (iiK[k] == jj) ? fbn : fxi[k];
        fxj[k] = (jjK[k] == ii) ? fan : fxj[k];
        fxj[k] = (jjK[k] == jj) ? fbn : fxj[k];
      }
    }

    // ---- output-bit maintenance (chain ql; lane segment seg = l&7) ----
    {
      const uint32_t ib = 1u << (ii & 31u);
      const uint32_t nv = (uint32_t)(-(int)ian) & ib;
      const bool own_i = ((uint32_t)seg == (ii >> 6));
      if ((ii >> 5) & 1u) { if (own_i) mhi = (mhi & ~ib) | nv; }
      else                { if (own_i) mlo = (mlo & ~ib) | nv; }
      const uint32_t jb = 1u << (jj & 31u);
      const uint32_t nj = (uint32_t)(-(int)ibn) & jb;
      const bool own_j = ((uint32_t)seg == (jj >> 6));
      if ((jj >> 5) & 1u) { if (own_j) mhi = (mhi & ~jb) | nj; }
      else                { if (own_j) mlo = (mlo & ~jb) | nj; }
    }
  }

  // ---- output: fully-coalesced stores (verbatim R8 epilogue) ----
  {
    float* wavebase = out + (size_t)chainbase * DDIM;
    #pragma unroll
    for (int g = 0; g < 16; ++g) {
      const int bidx = 16 * g + ((l >> 4) << 2);
      const uint32_t wlo = bpermu(bidx, mlo);
      const uint32_t whi = bpermu(bidx, mhi);
      const uint32_t w   = ((l >> 3) & 1) ? whi : wlo;
      const uint32_t nib = (w >> (4 * (l & 7))) & 0xFu;
      float4 o;
      o.x = (float)( nib       & 1u);
      o.y = (float)((nib >> 1) & 1u);
      o.z = (float)((nib >> 2) & 1u);
      o.w = (float)((nib >> 3) & 1u);
      *reinterpret_cast<float4*>(
          wavebase + (size_t)((g >> 1) * 512 + (64 * (g & 1) + l) * 4)) = o;
    }
  }
}

extern "C" void kernel_launch(void* const* d_in, const int* in_sizes, int n_in,
                              void* d_out, int out_size, void* d_ws, size_t ws_size,
                              hipStream_t stream) {
  const float* z = (const float*)d_in[0];   // (128, 512)
  const float* A = (const float*)d_in[1];   // (512, 512)
  const float* W = (const float*)d_in[2];   // (512, 512)
  float* out = (float*)d_out;               // (128, 128, 512)
  uint32_t* wsu = (uint32_t*)d_ws;
  float*    wsf = (float*)d_ws;

  hipLaunchKernelGGL(pre_kernel, dim3(MIX_TIME + 4 + 128), dim3(256), 0, stream,
                     A, W, z, wsu, wsf);
  hipLaunchKernelGGL(gibbs8_kernel, dim3(NCHAIN / 32), dim3(256), 0, stream,
                     A, wsu, wsf, out);
}

// Round 15
// 48.640 us; speedup vs baseline: 1.8858x; 1.0116x over previous
//
#include <hip/hip_runtime.h>
#include <stdint.h>

// ============================================================================
// Bit-exact JAX Gibbs sampler — R12 resubmit #3 (same pod unresponsive 3x).
// Owner-only steps: the slot-owner lane 8q+(t&7) holds ALL step-t inputs
// locally (slots + owner-layout gumbels); per step only {decision packet,
// St, Sz} cross lanes (3 bpermutes, 1 wait). Slot/mask updates deferred to
// the next step boundary. All value-producing arithmetic verbatim R11
// (absmax 0.0). pre_kernel unchanged from R8.
// ============================================================================
#define MIX_TIME 20
#define NCHAIN   16384   // S*B = 128*128
#define DDIM     512

// ws layout in 4-byte units
#define WS_TBL 0        // 80  (pad 128)
#define WS_SC  128      // 160
#define WS_T0  288      // 512
#define WS_U0  800      // 512
#define WS_ST0 1312     // 1 (pad 32)
#define WS_SZ0 1344     // 128
#define WS_C   1472     // 65536

struct U2 { uint32_t a, b; };

__device__ __forceinline__ uint32_t rotl32(uint32_t v, int r) {
  return (v << r) | (v >> (32 - r));
}

// Threefry-2x32, 20 rounds (JAX prng.py / Random123).
__device__ __forceinline__ U2 tf2x32(uint32_t k0, uint32_t k1, uint32_t x0, uint32_t x1) {
  const uint32_t ks2 = k0 ^ k1 ^ 0x1BD11BDAu;
  x0 += k0; x1 += k1;
  x0 += x1; x1 = rotl32(x1, 13); x1 ^= x0;
  x0 += x1; x1 = rotl32(x1, 15); x1 ^= x0;
  x0 += x1; x1 = rotl32(x1, 26); x1 ^= x0;
  x0 += x1; x1 = rotl32(x1,  6); x1 ^= x0;
  x0 += k1; x1 += ks2 + 1u;
  x0 += x1; x1 = rotl32(x1, 17); x1 ^= x0;
  x0 += x1; x1 = rotl32(x1, 29); x1 ^= x0;
  x0 += x1; x1 = rotl32(x1, 16); x1 ^= x0;
  x0 += x1; x1 = rotl32(x1, 24); x1 ^= x0;
  x0 += ks2; x1 += k0 + 2u;
  x0 += x1; x1 = rotl32(x1, 13); x1 ^= x0;
  x0 += x1; x1 = rotl32(x1, 15); x1 ^= x0;
  x0 += x1; x1 = rotl32(x1, 26); x1 ^= x0;
  x0 += x1; x1 = rotl32(x1,  6); x1 ^= x0;
  x0 += k0; x1 += k1 + 3u;
  x0 += x1; x1 = rotl32(x1, 17); x1 ^= x0;
  x0 += x1; x1 = rotl32(x1, 29); x1 ^= x0;
  x0 += x1; x1 = rotl32(x1, 16); x1 ^= x0;
  x0 += x1; x1 = rotl32(x1, 24); x1 ^= x0;
  x0 += k1; x1 += ks2 + 4u;
  x0 += x1; x1 = rotl32(x1, 13); x1 ^= x0;
  x0 += x1; x1 = rotl32(x1, 15); x1 ^= x0;
  x0 += x1; x1 = rotl32(x1, 26); x1 ^= x0;
  x0 += x1; x1 = rotl32(x1,  6); x1 ^= x0;
  x0 += ks2; x1 += k0 + 5u;
  return {x0, x1};
}

// partitionable threefry (validated bit-exact in R1-R11)
__device__ __forceinline__ uint32_t rbits32(uint32_t k0, uint32_t k1, uint32_t m) {
  U2 r = tf2x32(k0, k1, 0u, m);
  return r.a ^ r.b;
}
__device__ __forceinline__ U2 split_key(uint32_t k0, uint32_t k1, uint32_t idx) {
  return tf2x32(k0, k1, 0u, idx);
}

// gumbel from raw bits — expression identical to R1-R11 (bit-exact g)
__device__ __forceinline__ float gumbel_from(uint32_t bits) {
  float u = __uint_as_float(0x3f800000u | (bits >> 9)) - 1.0f;
  u = fmaxf(u + 1.17549435e-38f, 1.17549435e-38f);
  return -logf(-logf(u));
}

__device__ __forceinline__ float bpermf(int byteidx, float v) {
  return __int_as_float(__builtin_amdgcn_ds_bpermute(byteidx, __float_as_int(v)));
}
__device__ __forceinline__ uint32_t bpermu(int byteidx, uint32_t v) {
  return (uint32_t)__builtin_amdgcn_ds_bpermute(byteidx, (int)v);
}

// ============================================================================
// Kernel A (unchanged from R8): bid 0..19: one sort each (+sc row) |
// 20,21: T0 (+St0) | 22,23: U0 | 24..151: C z-batched slabs (+Sz0 in slab 0)
// ============================================================================
__global__ __launch_bounds__(256)
void pre_kernel(const float* __restrict__ A, const float* __restrict__ W,
                const float* __restrict__ z, uint32_t* __restrict__ wsu,
                float* __restrict__ wsf) {
  const int bid = blockIdx.x, tid = threadIdx.x;
  uint32_t* tbl = wsu + WS_TBL;
  uint32_t* sc  = wsu + WS_SC;
  float* T0  = wsf + WS_T0;
  float* U0  = wsf + WS_U0;
  float* St0 = wsf + WS_ST0;
  float* Sz0 = wsf + WS_SZ0;
  float* C   = wsf + WS_C;

  __shared__ float  sred[64];
  __shared__ float4 zs4[8][128];
  __shared__ float  credL[8][64];

  if (bid < MIX_TIME) {
    if (tid >= 64) return;
    const uint32_t t    = (uint32_t)bid;
    const uint32_t lane = (uint32_t)tid;
    const U2 K   = split_key(0u, 1u, t);
    const U2 ki  = split_key(K.a, K.b, 0u);
    const U2 ks  = split_key(K.a, K.b, 1u);
    const U2 sub = split_key(ki.a, ki.b, 1u);

    uint32_t k1 = 0xFFFFFFFFu, m1 = 0xFFFFFFFFu;
    uint32_t k2 = 0xFFFFFFFFu, m2 = 0xFFFFFFFFu;
    #pragma unroll
    for (int p = 0; p < 8; ++p) {
      const uint32_t m   = lane + 64u * (uint32_t)p;
      const uint32_t key = rbits32(sub.a, sub.b, m);
      const bool lt1 = (key < k1) || (key == k1 && m < m1);
      const bool lt2 = (key < k2) || (key == k2 && m < m2);
      if (lt1)      { k2 = k1; m2 = m1; k1 = key; m1 = m; }
      else if (lt2) { k2 = key; m2 = m; }
    }
    #pragma unroll
    for (int msk = 1; msk < 64; msk <<= 1) {
      const uint32_t ok1 = __shfl_xor((int)k1, msk, 64);
      const uint32_t om1 = __shfl_xor((int)m1, msk, 64);
      const uint32_t ok2 = __shfl_xor((int)k2, msk, 64);
      const uint32_t om2 = __shfl_xor((int)m2, msk, 64);
      const bool oless = (ok1 < k1) || (ok1 == k1 && om1 < m1);
      if (oless) {
        const bool l2 = (k1 < ok2) || (k1 == ok2 && m1 < om2);
        const uint32_t nk2 = l2 ? k1 : ok2, nm2 = l2 ? m1 : om2;
        k1 = ok1; m1 = om1; k2 = nk2; m2 = nm2;
      } else {
        const bool l2 = (ok1 < k2) || (ok1 == k2 && om1 < m2);
        if (l2) { k2 = ok1; m2 = om1; }
      }
    }
    if (lane == 0) {
      tbl[4u * t + 0u] = m1;
      tbl[4u * t + 1u] = m2;
      tbl[4u * t + 2u] = ks.a;
      tbl[4u * t + 3u] = ks.b;
      sc[8u * t + 0u] = m1;
      sc[8u * t + 1u] = m2;
      sc[8u * t + 6u] = 0u;
      sc[8u * t + 7u] = 0u;
    }
    if (lane < 4) {   // Aii, Aij, Aji, Ajj
      const uint32_t r = (lane < 2) ? m1 : m2;
      const uint32_t c = (lane & 1) ? m2 : m1;
      sc[8u * t + 2u + lane] = __float_as_uint(A[(size_t)r * DDIM + c]);
    }
    return;
  }

  if (bid <= MIX_TIME + 1) {         // T0[e] = sum_{d<64} A[d,e] (+St0)
    const int e = (bid - MIX_TIME) * 256 + tid;
    float s = 0.f;
    #pragma unroll 1
    for (int d = 0; d < 64; ++d) s += A[(size_t)d * DDIM + e];
    T0[e] = s;
    if (bid == MIX_TIME) {
      if (tid < 64) sred[tid] = s;
      __syncthreads();
      if (tid == 0) {
        float q = 0.f;
        #pragma unroll 1
        for (int e2 = 0; e2 < 64; ++e2) q += sred[e2];
        St0[0] = q;
      }
    }
    return;
  }

  if (bid <= MIX_TIME + 3) {         // U0[d] = sum_{e<64} A[d,e]
    const int d = (bid - MIX_TIME - 2) * 256 + tid;
    const float4* Ar = reinterpret_cast<const float4*>(A + (size_t)d * DDIM);
    float s = 0.f;
    #pragma unroll
    for (int k = 0; k < 16; ++k) {
      const float4 v = Ar[k];
      s += v.x; s += v.y; s += v.z; s += v.w;
    }
    U0[d] = s;
    return;
  }

  // ---- C[b][d] = sum_k W[d,k] z[b,k]: block = (bg of 8 b's, slab of 64 d's) ----
  const int cb = bid - (MIX_TIME + 4);  // 0..127
  const int bg = cb >> 3, slab = cb & 7;
  #pragma unroll
  for (int k = 0; k < 4; ++k) {
    const int idx = tid + 256 * k;      // 0..1023 = brow*128 + col4
    const int br = idx >> 7, c4i = idx & 127;
    zs4[br][c4i] = reinterpret_cast<const float4*>(z + (size_t)(bg * 8 + br) * DDIM)[c4i];
  }
  __syncthreads();
  const int r = tid & 63;
  const int h = tid >> 6;               // b pair {2h, 2h+1}
  const int d = slab * 64 + r;
  const float4* Wr = reinterpret_cast<const float4*>(W + (size_t)d * DDIM);
  float s0 = 0.f, s1 = 0.f;
  #pragma unroll 4
  for (int k = 0; k < 128; ++k) {
    const float4 w = Wr[k];
    const float4 za = zs4[2 * h][k], zb = zs4[2 * h + 1][k];
    s0 = fmaf(w.x, za.x, s0); s0 = fmaf(w.y, za.y, s0);
    s0 = fmaf(w.z, za.z, s0); s0 = fmaf(w.w, za.w, s0);
    s1 = fmaf(w.x, zb.x, s1); s1 = fmaf(w.y, zb.y, s1);
    s1 = fmaf(w.z, zb.z, s1); s1 = fmaf(w.w, zb.w, s1);
  }
  C[(size_t)(bg * 8 + 2 * h) * DDIM + d]     = s0;
  C[(size_t)(bg * 8 + 2 * h + 1) * DDIM + d] = s1;
  if (slab == 0) { credL[2 * h][r] = s0; credL[2 * h + 1][r] = s1; }
  __syncthreads();
  if (slab == 0 && tid < 8) {
    float s = 0.f;
    #pragma unroll 1
    for (int e = 0; e < 64; ++e) s += credL[tid][e];
    Sz0[bg * 8 + tid] = s;
  }
}

// ============================================================================
// Kernel B: sampler, 8 chains/wave, owner-only steps.
//   Slot (q, t') at lane 8q + (t'&7), reg set t'>>3. Owner of step t is lane
//   8q + (t&7): it holds all step-t inputs locally (incl. gumbels g2[k][c]).
//   Per step boundary: 3 bpermutes {pk, St, Sz} from the previous owner, then
//   deferred slot/mask updates, then the local step-t compute.
// ============================================================================
__global__ __launch_bounds__(256)
void gibbs8_kernel(const float* __restrict__ A,
                   const uint32_t* __restrict__ wsu,
                   const float* __restrict__ wsf,
                   float* __restrict__ out) {
  const int tid = threadIdx.x;
  const int l = tid & 63, wv = tid >> 6;
  const uint32_t* tbl = wsu + WS_TBL;
  const uint32_t* sc  = wsu + WS_SC;
  const float* T0w  = wsf + WS_T0;
  const float* U0w  = wsf + WS_U0;
  const float* St0w = wsf + WS_ST0;
  const float* Sz0w = wsf + WS_SZ0;
  const float* Cw   = wsf + WS_C;

  __shared__ __align__(16) float gg[3200];   // [0,1600)=G, [1600,3200)=Gt
  __shared__ uint32_t tblL[80];
  if (tid < 80) tblL[tid] = tbl[tid];
  __syncthreads();
  #pragma unroll 1
  for (int p = tid; p < 1600; p += 256) {
    const int r = p / 40, c = p % 40;
    const uint32_t cr = tblL[4 * (r >> 1) + (r & 1)];
    const uint32_t cc = tblL[4 * (c >> 1) + (c & 1)];
    gg[p]        = A[(size_t)cr * DDIM + cc];
    gg[1600 + p] = A[(size_t)cc * DDIM + cr];
  }

  const int ql  = l >> 3;   // chain (algebra + slots + output bits)
  const int seg = l & 7;    // slot t'-low-bits / output segment
  const uint32_t chainbase = ((uint32_t)blockIdx.x * 4u + (uint32_t)wv) * 8u;
  const uint32_t chain_l = chainbase + (uint32_t)ql;
  const uint32_t b_l = chain_l & 127u;

  // ---- state: slot (q=ql, t' = 8k + seg); values identical to R8/R11 ----
  float fTi[3], fTj[3], fUi[3], fUj[3], fci[3], fcj[3], fxi[3], fxj[3];
  uint32_t iiK[3], jjK[3];
  const float* ggb[3];
  #pragma unroll
  for (int k = 0; k < 3; ++k) {
    const int tp = 8 * k + seg;
    const int tc = (tp < MIX_TIME) ? tp : 0;
    const uint32_t i = sc[8 * tc], j = sc[8 * tc + 1];
    iiK[k] = i; jjK[k] = j;
    fTi[k] = T0w[i];  fTj[k] = T0w[j];
    fUi[k] = U0w[i];  fUj[k] = U0w[j];
    fci[k] = Cw[(size_t)b_l * DDIM + i];
    fcj[k] = Cw[(size_t)b_l * DDIM + j];
    fxi[k] = (i < 64u) ? 1.f : 0.f;
    fxj[k] = (j < 64u) ? 1.f : 0.f;
    ggb[k] = &gg[2 * tc];
  }
  float St = St0w[0];
  float Sz = Sz0w[b_l];
  uint32_t mlo = (seg == 0) ? 0xFFFFFFFFu : 0u;
  uint32_t mhi = mlo;
  int pk = 0;

  // ---- gumbels in OWNER layout: lane 8q+seg holds g2[k][c] for t=8k+seg.
  //      Same keys/counters as R8/R11 -> bit-exact values. ----
  float g2[3][4];
  #pragma unroll
  for (int k = 0; k < 3; ++k) {
    const int tp = 8 * k + seg;
    const int tc = (tp < MIX_TIME) ? tp : 0;
    const uint32_t k0g = tbl[4 * tc + 2], k1g = tbl[4 * tc + 3];
    #pragma unroll
    for (int c = 0; c < 4; ++c)
      g2[k][c] = gumbel_from(rbits32(k0g, k1g, chain_l * 4u + (uint32_t)c));
  }
  __syncthreads();

  #pragma unroll
  for (int t = 0; t < MIX_TIME; ++t) {
    // ---- boundary: apply decision s = t-1 (from prev owner), carry St/Sz ----
    if (t > 0) {
      const int s = t - 1;
      const int srcb = ((l & 0x38) + (s & 7)) << 2;
      const int   pks = __builtin_amdgcn_ds_bpermute(srcb, pk);
      const float StP = bpermf(srcb, St);
      const float SzP = bpermf(srcb, Sz);
      St = StP; Sz = SzP;
      const float fdi_s = (float)((pks & 3) - 1);
      const float fdj_s = (float)(((pks >> 2) & 3) - 1);
      const int ian_s = (pks >> 5) & 1, ibn_s = (pks >> 4) & 1;
      const float fan_s = (float)ian_s, fbn_s = (float)ibn_s;
      const uint32_t iiP = sc[8 * s], jjP = sc[8 * s + 1];

      #pragma unroll
      for (int k = 0; k < 3; ++k) {
        if (s < 8 * k + 7) {
          const float2 ga = *reinterpret_cast<const float2*>(ggb[k] + 80 * s);
          const float2 gB = *reinterpret_cast<const float2*>(ggb[k] + 80 * s + 40);
          const float2 gc = *reinterpret_cast<const float2*>(ggb[k] + 1600 + 80 * s);
          const float2 gd = *reinterpret_cast<const float2*>(ggb[k] + 1600 + 80 * s + 40);
          fTi[k] = fmaf(fdi_s, ga.x, fmaf(fdj_s, gB.x, fTi[k]));
          fTj[k] = fmaf(fdi_s, ga.y, fmaf(fdj_s, gB.y, fTj[k]));
          fUi[k] = fmaf(fdi_s, gc.x, fmaf(fdj_s, gd.x, fUi[k]));
          fUj[k] = fmaf(fdi_s, gc.y, fmaf(fdj_s, gd.y, fUj[k]));
          fxi[k] = (iiK[k] == iiP) ? fan_s : fxi[k];
          fxi[k] = (iiK[k] == jjP) ? fbn_s : fxi[k];
          fxj[k] = (jjK[k] == iiP) ? fan_s : fxj[k];
          fxj[k] = (jjK[k] == jjP) ? fbn_s : fxj[k];
        }
      }
      // output-bit maintenance for decision s
      {
        const uint32_t ib = 1u << (iiP & 31u);
        const uint32_t nv = (uint32_t)(-ian_s) & ib;
        const bool own_i = ((uint32_t)seg == (iiP >> 6));
        if ((iiP >> 5) & 1u) { if (own_i) mhi = (mhi & ~ib) | nv; }
        else                 { if (own_i) mlo = (mlo & ~ib) | nv; }
        const uint32_t jb = 1u << (jjP & 31u);
        const uint32_t nj = (uint32_t)(-ibn_s) & jb;
        const bool own_j = ((uint32_t)seg == (jjP >> 6));
        if ((jjP >> 5) & 1u) { if (own_j) mhi = (mhi & ~jb) | nj; }
        else                 { if (own_j) mlo = (mlo & ~jb) | nj; }
      }
    }

    // ---- local step-t compute (valid on owner lane 8q+(t&7) only) ----
    const int kS = t >> 3;
    const float Ti  = fTi[kS], Tj  = fTj[kS];
    const float Ui  = fUi[kS], Uj  = fUj[kS];
    const float cib = fci[kS], cjb = fcj[kS];
    const float xi  = fxi[kS], xj  = fxj[kS];

    const float Aii = __uint_as_float(sc[8 * t + 2]);
    const float Aij = __uint_as_float(sc[8 * t + 3]);
    const float Aji = __uint_as_float(sc[8 * t + 4]);
    const float Ajj = __uint_as_float(sc[8 * t + 5]);

    // ---- algebra (R4-R11 verbatim) ----
    const float si   = Ui - xi * Aii - xj * Aij;
    const float sj   = Uj - xi * Aji - xj * Ajj;
    const float sTR  = St - xi * Ti - xj * Tj;
    const float szR  = Sz - xi * cib - xj * cjb;
    const float QR   = sTR - xi * si - xj * sj;
    const float coli = Ti - xi * Aii - xj * Aji;
    const float colj = Tj - xi * Aij - xj * Ajj;
    const float base = QR + szR;
    const float gi   = si + coli + Aii + cib;
    const float gj   = sj + colj + Ajj + cjb;
    const float gij  = Aij + Aji;

    const float v0 = g2[kS][0] + base;
    const float v1 = g2[kS][1] + (base + gj);
    const float v2 = g2[kS][2] + (base + gi);
    const float v3 = g2[kS][3] + (base + gi + gj + gij);

    // first-max argmax, purely local (strict > keeps lowest index)
    int bestc = 0; float bv = v0;
    if (v1 > bv) { bv = v1; bestc = 1; }
    if (v2 > bv) { bv = v2; bestc = 2; }
    if (v3 > bv) { bv = v3; bestc = 3; }

    const int ian = (bestc >> 1) & 1, ibn = bestc & 1;
    const float fan = (float)ian, fbn = (float)ibn;
    const float fdi = fan - xi, fdj = fbn - xj;

    St = St + fdi * Ti + fdj * Tj
            + fdi * (si + fan * Aii + fbn * Aij)
            + fdj * (sj + fan * Aji + fbn * Ajj);
    Sz = Sz + fdi * cib + fdj * cjb;

    pk = ((int)fdi + 1) | (((int)fdj + 1) << 2) | (bestc << 4);
  }

  // ---- final flush: decision s = 19 -> output masks only ----
  {
    const int s = MIX_TIME - 1;
    const int srcb = ((l & 0x38) + (s & 7)) << 2;
    const int pks = __builtin_amdgcn_ds_bpermute(srcb, pk);
    const int ian_s = (pks >> 5) & 1, ibn_s = (pks >> 4) & 1;
    const uint32_t iiP = sc[8 * s], jjP = sc[8 * s + 1];
    const uint32_t ib = 1u << (iiP & 31u);
    const uint32_t nv = (uint32_t)(-ian_s) & ib;
    const bool own_i = ((uint32_t)seg == (iiP >> 6));
    if ((iiP >> 5) & 1u) { if (own_i) mhi = (mhi & ~ib) | nv; }
    else                 { if (own_i) mlo = (mlo & ~ib) | nv; }
    const uint32_t jb = 1u << (jjP & 31u);
    const uint32_t nj = (uint32_t)(-ibn_s) & jb;
    const bool own_j = ((uint32_t)seg == (jjP >> 6));
    if ((jjP >> 5) & 1u) { if (own_j) mhi = (mhi & ~jb) | nj; }
    else                 { if (own_j) mlo = (mlo & ~jb) | nj; }
  }

  // ---- output: fully-coalesced stores (verbatim R8 epilogue) ----
  {
    float* wavebase = out + (size_t)chainbase * DDIM;
    #pragma unroll
    for (int g = 0; g < 16; ++g) {
      const int bidx = 16 * g + ((l >> 4) << 2);
      const uint32_t wlo = bpermu(bidx, mlo);
      const uint32_t whi = bpermu(bidx, mhi);
      const uint32_t w   = ((l >> 3) & 1) ? whi : wlo;
      const uint32_t nib = (w >> (4 * (l & 7))) & 0xFu;
      float4 o;
      o.x = (float)( nib       & 1u);
      o.y = (float)((nib >> 1) & 1u);
      o.z = (float)((nib >> 2) & 1u);
      o.w = (float)((nib >> 3) & 1u);
      *reinterpret_cast<float4*>(
          wavebase + (size_t)((g >> 1) * 512 + (64 * (g & 1) + l) * 4)) = o;
    }
  }
}

extern "C" void kernel_launch(void* const* d_in, const int* in_sizes, int n_in,
                              void* d_out, int out_size, void* d_ws, size_t ws_size,
                              hipStream_t stream) {
  const float* z = (const float*)d_in[0];   // (128, 512)
  const float* A = (const float*)d_in[1];   // (512, 512)
  const float* W = (const float*)d_in[2];   // (512, 512)
  float* out = (float*)d_out;               // (128, 128, 512)
  uint32_t* wsu = (uint32_t*)d_ws;
  float*    wsf = (float*)d_ws;

  hipLaunchKernelGGL(pre_kernel, dim3(MIX_TIME + 4 + 128), dim3(256), 0, stream,
                     A, W, z, wsu, wsf);
  hipLaunchKernelGGL(gibbs8_kernel, dim3(NCHAIN / 32), dim3(256), 0, stream,
                     A, wsu, wsf, out);
}